// Round 4
// baseline (366.971 us; speedup 1.0000x reference)
//
#include <hip/hip_runtime.h>
#include <hip/hip_bf16.h>

// 1-NN VQ via split-bf16 MFMA + exact fp32 refinement.
//   score[q][k] = csq[k] - 2*dot(q,c_k); out = argmin_k (lowest-k tie-break).
// Phase 0 (knn_prep): codebook -> bf16 hi/lo fragment-ready cbB in d_ws + csq.
// Phase A (knn_mfma): per block 128 queries; q split to (qh,ql) bf16 in LDS;
//   dot = (qh+ql).(ch+cl) exactly via 4 cross-products (K=512 eff) with
//   mfma_f32_16x16x32_bf16. Per query: best+second (u64 monotone keys);
//   gap < T -> append to worklist (error bound ~2e-3 << T=0.25).
// Phase B (knn_refine): exact fp32 rescan of flagged queries (round-3 math).

typedef __bf16 bf16x8 __attribute__((ext_vector_type(8)));
typedef float  floatx4 __attribute__((ext_vector_type(4)));
typedef unsigned uintx4 __attribute__((ext_vector_type(4)));

#define MFMA16 __builtin_amdgcn_mfma_f32_16x16x32_bf16

#define CNT_OFF 0
#define CSQ_OFF 1024
#define CBB_OFF 4096
#define WL_OFF  (4096 + 131072)
#define T_FLAG  0.25f

__device__ __forceinline__ unsigned fmap(float f) {
    unsigned u = __float_as_uint(f);
    return (u & 0x80000000u) ? ~u : (u | 0x80000000u);
}
__device__ __forceinline__ float unfmap(unsigned u) {
    unsigned b = (u & 0x80000000u) ? (u ^ 0x80000000u) : ~u;
    return __uint_as_float(b);
}

// ---------------- Phase 0: codebook split + fragment layout + csq ----------------
// cbB cell id = (t*8 + kb)*64 + lane, 8 bf16 each. t = n-tile (16 codes),
// kb<4: ch chunk kb; kb>=4: cl chunk kb-4. lane: n = t*16+(lane&15),
// k = chunk*32 + (lane>>4)*8 + j.
__global__ void knn_prep(const float* __restrict__ cb, __bf16* __restrict__ cbB,
                         float* __restrict__ csq) {
    const int tid = threadIdx.x;
    const int id = blockIdx.x * 256 + tid;       // 0..8191
    const int t = id >> 9;
    const int kb = (id >> 6) & 7;
    const int ln = id & 63;
    const int n = t * 16 + (ln & 15);
    const int part = kb >> 2;
    const int chunk = kb & 3;
    const int k0 = chunk * 32 + (ln >> 4) * 8;
    const float* src = cb + (size_t)n * 128 + k0;
    union { __bf16 h[8]; uintx4 u; } p;
#pragma unroll
    for (int j = 0; j < 8; ++j) {
        float f = src[j];
        __bf16 hh = (__bf16)f;
        p.h[j] = (part == 0) ? hh : (__bf16)(f - (float)hh);
    }
    *(uintx4*)(cbB + (size_t)id * 8) = p.u;

    if (blockIdx.x == 0) {
        const float4* row = (const float4*)(cb + (size_t)tid * 128);
        float a0 = 0.f, a1 = 0.f, a2 = 0.f, a3 = 0.f;
#pragma unroll
        for (int j = 0; j < 32; ++j) {
            float4 v = row[j];
            a0 = fmaf(v.x, v.x, a0);
            a1 = fmaf(v.y, v.y, a1);
            a2 = fmaf(v.z, v.z, a2);
            a3 = fmaf(v.w, v.w, a3);
        }
        csq[tid] = (a0 + a1) + (a2 + a3);
    }
}

// ---------------- Phase A: MFMA scores + top-2 + flag ----------------
__global__ __launch_bounds__(256, 2) void knn_mfma(const float* __restrict__ x,
                                                   const __bf16* __restrict__ cbB,
                                                   const float* __restrict__ csq_g,
                                                   int* __restrict__ out,
                                                   int* __restrict__ cnt,
                                                   int* __restrict__ wl) {
    __shared__ __bf16 sAf[8 * 8 * 64 * 8];   // [mt][kb][lane][8] = 64 KB
    __shared__ float s_csq[256];

    const int tid = threadIdx.x;
    const int wave = tid >> 6;
    const int lane = tid & 63;

    s_csq[tid] = csq_g[tid];

    // ---- convert query tile to split bf16, fragment-ready in LDS ----
    const float* xblk = x + (size_t)blockIdx.x * 128 * 128;
    const int chunk = (tid >> 6) & 3;
    const int ln = tid & 63;
#pragma unroll
    for (int mt = 0; mt < 8; ++mt) {
        const int q = mt * 16 + (ln & 15);
        const int k0 = chunk * 32 + (ln >> 4) * 8;
        const float* src = xblk + (size_t)q * 128 + k0;
        float4 f0 = *(const float4*)(src);
        float4 f1 = *(const float4*)(src + 4);
        float f[8] = {f0.x, f0.y, f0.z, f0.w, f1.x, f1.y, f1.z, f1.w};
        union { __bf16 h[8]; uintx4 u; } ph, pl;
#pragma unroll
        for (int j = 0; j < 8; ++j) {
            __bf16 hh = (__bf16)f[j];
            ph.h[j] = hh;
            pl.h[j] = (__bf16)(f[j] - (float)hh);
        }
        *(uintx4*)(sAf + (((mt * 8 + chunk) * 64 + ln) * 8)) = ph.u;
        *(uintx4*)(sAf + (((mt * 8 + 4 + chunk) * 64 + ln) * 8)) = pl.u;
    }
    __syncthreads();

    // ---- main loop: wave owns m-tiles {2w, 2w+1} x all 16 n-tiles ----
    floatx4 acc[2][16];
#pragma unroll
    for (int m = 0; m < 2; ++m)
#pragma unroll
        for (int t = 0; t < 16; ++t) acc[m][t] = (floatx4){0.f, 0.f, 0.f, 0.f};

    const int mt0 = wave * 2;
#pragma unroll
    for (int kb = 0; kb < 8; ++kb) {
        const int ca = kb & 3;
        bf16x8 ah0 = *(bf16x8*)(sAf + (((mt0 * 8 + ca) * 64 + lane) * 8));
        bf16x8 al0 = *(bf16x8*)(sAf + (((mt0 * 8 + 4 + ca) * 64 + lane) * 8));
        bf16x8 ah1 = *(bf16x8*)(sAf + ((((mt0 + 1) * 8 + ca) * 64 + lane) * 8));
        bf16x8 al1 = *(bf16x8*)(sAf + ((((mt0 + 1) * 8 + 4 + ca) * 64 + lane) * 8));
        const __bf16* bbase = cbB + ((size_t)kb * 64 + lane) * 8;
#pragma unroll
        for (int t = 0; t < 16; ++t) {
            bf16x8 b = *(const bf16x8*)(bbase + (size_t)t * 4096);
            acc[0][t] = MFMA16(ah0, b, acc[0][t], 0, 0, 0);
            acc[1][t] = MFMA16(ah1, b, acc[1][t], 0, 0, 0);
            acc[0][t] = MFMA16(al0, b, acc[0][t], 0, 0, 0);
            acc[1][t] = MFMA16(al1, b, acc[1][t], 0, 0, 0);
        }
    }

    // ---- epilogue: top-2 per query row, flag near-ties ----
    float cs[16];
#pragma unroll
    for (int t = 0; t < 16; ++t) cs[t] = s_csq[t * 16 + (lane & 15)];

#pragma unroll
    for (int m = 0; m < 2; ++m) {
        const int mt = mt0 + m;
#pragma unroll
        for (int r = 0; r < 4; ++r) {
            unsigned long long b = ~0ULL, s = ~0ULL;
#pragma unroll
            for (int t = 0; t < 16; ++t) {
                const int n = t * 16 + (lane & 15);
                float score = fmaf(-2.0f, acc[m][t][r], cs[t]);
                unsigned long long key =
                    ((unsigned long long)fmap(score) << 32) | (unsigned)n;
                if (key < b) { s = b; b = key; }
                else if (key < s) { s = key; }
            }
#pragma unroll
            for (int d = 1; d < 16; d <<= 1) {
                unsigned long long ob = __shfl_xor(b, d);
                unsigned long long os = __shfl_xor(s, d);
                unsigned long long nb = ob < b ? ob : b;
                unsigned long long mx = ob < b ? b : ob;
                unsigned long long mn = os < s ? os : s;
                b = nb;
                s = mx < mn ? mx : mn;
            }
            if ((lane & 15) == 0) {
                const int row = (lane >> 4) * 4 + r;
                const size_t qg = (size_t)blockIdx.x * 128 + mt * 16 + row;
                out[qg] = (int)(unsigned)(b & 0xFFFFFFFFull);
                float f1 = unfmap((unsigned)(b >> 32));
                float f2 = unfmap((unsigned)(s >> 32));
                if (f2 - f1 < T_FLAG) {
                    int idx = atomicAdd(cnt, 1);
                    wl[idx] = (int)qg;
                }
            }
        }
    }
}

// ---------------- Phase B: exact fp32 rescan of flagged queries ----------------
__global__ __launch_bounds__(256) void knn_refine(const float* __restrict__ x,
                                                  const float* __restrict__ cb,
                                                  const int* __restrict__ wl,
                                                  const int* __restrict__ cnt,
                                                  int* __restrict__ out) {
    const int wave = threadIdx.x >> 6;
    const int lane = threadIdx.x & 63;
    const int gw = blockIdx.x * 4 + wave;
    const int n = *cnt;
    const int stride = gridDim.x * 4;

    for (int i = gw; i < n; i += stride) {
        const int q = wl[i];
        const float4* qr = (const float4*)(x + (size_t)q * 128);
        unsigned long long best = ~0ULL;
#pragma unroll
        for (int j = 0; j < 4; ++j) {
            const int k = j * 64 + lane;
            const float4* cr = (const float4*)(cb + (size_t)k * 128);
            float a0 = 0.f, a1 = 0.f, a2 = 0.f, a3 = 0.f;
            float c0 = 0.f, c1 = 0.f, c2 = 0.f, c3 = 0.f;
#pragma unroll
            for (int c4 = 0; c4 < 32; ++c4) {
                float4 cv = cr[c4];
                float4 qv = qr[c4];
                a0 = fmaf(qv.x, cv.x, a0);
                a1 = fmaf(qv.y, cv.y, a1);
                a2 = fmaf(qv.z, cv.z, a2);
                a3 = fmaf(qv.w, cv.w, a3);
                c0 = fmaf(cv.x, cv.x, c0);
                c1 = fmaf(cv.y, cv.y, c1);
                c2 = fmaf(cv.z, cv.z, c2);
                c3 = fmaf(cv.w, cv.w, c3);
            }
            float dot = (a0 + a1) + (a2 + a3);
            float csq = (c0 + c1) + (c2 + c3);
            float score = fmaf(-2.0f, dot, csq);
            unsigned long long key =
                ((unsigned long long)fmap(score) << 32) | (unsigned)k;
            best = key < best ? key : best;
        }
#pragma unroll
        for (int d = 1; d < 64; d <<= 1) {
            unsigned long long o = __shfl_xor(best, d);
            best = o < best ? o : best;
        }
        if (lane == 0)
            out[q] = (int)(unsigned)(best & 0xFFFFFFFFull);
    }
}

extern "C" void kernel_launch(void* const* d_in, const int* in_sizes, int n_in,
                              void* d_out, int out_size, void* d_ws, size_t ws_size,
                              hipStream_t stream) {
    const float* x = (const float*)d_in[0];
    const float* cb = (const float*)d_in[1];
    int* out = (int*)d_out;

    char* ws = (char*)d_ws;
    int* cnt = (int*)(ws + CNT_OFF);
    float* csq = (float*)(ws + CSQ_OFF);
    __bf16* cbB = (__bf16*)(ws + CBB_OFF);
    int* wl = (int*)(ws + WL_OFF);

    const int M = in_sizes[0] / 128;     // 131072

    hipMemsetAsync(cnt, 0, 4, stream);
    knn_prep<<<32, 256, 0, stream>>>(cb, cbB, csq);
    knn_mfma<<<M / 128, 256, 0, stream>>>(x, cbB, csq, out, cnt, wl);
    knn_refine<<<512, 256, 0, stream>>>(x, cb, wl, cnt, out);
}

// Round 5
// 201.620 us; speedup vs baseline: 1.8201x; 1.8201x over previous
//
#include <hip/hip_runtime.h>
#include <hip/hip_bf16.h>

// 1-NN VQ via split-bf16 MFMA + exact fp32 refinement.
//   score[q][k] = csq[k] - 2*dot(q,c_k); out = argmin_k (lowest-k tie-break).
// Phase 0 (knn_prep): codebook -> bf16 hi/lo fragment-ready cbB in d_ws + csq.
// Phase A (knn_mfma): 128 queries/block; q split to (qh,ql) bf16 in LDS;
//   dot = (qh+ql).(ch+cl) exactly via 4 cross-products, mfma_f32_16x16x32_bf16.
//   Top-2 per query via monotone u64 keys; gap < T=0.02 -> worklist.
//   (Split-product error bound ~2e-3 << T. Round-4 evidence: unflagged
//   queries matched np exactly -> layouts + precision verified.)
// Phase B (knn_refine): exact fp32 rescan of flagged queries only.
// Round-5 changes: kb-loop unroll 1 (kill spill: r4 had VGPR=256 + scratch),
//   T 0.25->0.02 (n ~7k -> ~300), refine unroll 1 (kill its spill), wl cap.

typedef __bf16 bf16x8 __attribute__((ext_vector_type(8)));
typedef float  floatx4 __attribute__((ext_vector_type(4)));
typedef unsigned uintx4 __attribute__((ext_vector_type(4)));

#define MFMA16 __builtin_amdgcn_mfma_f32_16x16x32_bf16

#define CNT_OFF 0
#define CSQ_OFF 1024
#define CBB_OFF 4096
#define WL_OFF  (4096 + 131072)
#define WL_CAP  32768
#define T_FLAG  0.02f

__device__ __forceinline__ unsigned fmap(float f) {
    unsigned u = __float_as_uint(f);
    return (u & 0x80000000u) ? ~u : (u | 0x80000000u);
}
__device__ __forceinline__ float unfmap(unsigned u) {
    unsigned b = (u & 0x80000000u) ? (u ^ 0x80000000u) : ~u;
    return __uint_as_float(b);
}

// ---------------- Phase 0: codebook split + fragment layout + csq ----------------
__global__ void knn_prep(const float* __restrict__ cb, __bf16* __restrict__ cbB,
                         float* __restrict__ csq) {
    const int tid = threadIdx.x;
    const int id = blockIdx.x * 256 + tid;       // 0..8191
    const int t = id >> 9;
    const int kb = (id >> 6) & 7;
    const int ln = id & 63;
    const int n = t * 16 + (ln & 15);
    const int part = kb >> 2;
    const int chunk = kb & 3;
    const int k0 = chunk * 32 + (ln >> 4) * 8;
    const float* src = cb + (size_t)n * 128 + k0;
    union { __bf16 h[8]; uintx4 u; } p;
#pragma unroll
    for (int j = 0; j < 8; ++j) {
        float f = src[j];
        __bf16 hh = (__bf16)f;
        p.h[j] = (part == 0) ? hh : (__bf16)(f - (float)hh);
    }
    *(uintx4*)(cbB + (size_t)id * 8) = p.u;

    if (blockIdx.x == 0) {
        const float4* row = (const float4*)(cb + (size_t)tid * 128);
        float a0 = 0.f, a1 = 0.f, a2 = 0.f, a3 = 0.f;
#pragma unroll 8
        for (int j = 0; j < 32; ++j) {
            float4 v = row[j];
            a0 = fmaf(v.x, v.x, a0);
            a1 = fmaf(v.y, v.y, a1);
            a2 = fmaf(v.z, v.z, a2);
            a3 = fmaf(v.w, v.w, a3);
        }
        csq[tid] = (a0 + a1) + (a2 + a3);
    }
}

// ---------------- Phase A: MFMA scores + top-2 + flag ----------------
__global__ __launch_bounds__(256, 2) void knn_mfma(const float* __restrict__ x,
                                                   const __bf16* __restrict__ cbB,
                                                   const float* __restrict__ csq_g,
                                                   int* __restrict__ out,
                                                   int* __restrict__ cnt,
                                                   int* __restrict__ wl) {
    __shared__ __bf16 sAf[8 * 8 * 64 * 8];   // [mt][kb][lane][8] = 64 KB
    __shared__ float s_csq[256];

    const int tid = threadIdx.x;
    const int wave = tid >> 6;
    const int lane = tid & 63;

    s_csq[tid] = csq_g[tid];

    // ---- convert query tile to split bf16, fragment-ready in LDS ----
    const float* xblk = x + (size_t)blockIdx.x * 128 * 128;
    const int chunk = wave;                  // wave w converts channel chunk w
    const int ln = tid & 63;
#pragma unroll 1
    for (int mt = 0; mt < 8; ++mt) {
        const int q = mt * 16 + (ln & 15);
        const int k0 = chunk * 32 + (ln >> 4) * 8;
        const float* src = xblk + (size_t)q * 128 + k0;
        float4 f0 = *(const float4*)(src);
        float4 f1 = *(const float4*)(src + 4);
        float f[8] = {f0.x, f0.y, f0.z, f0.w, f1.x, f1.y, f1.z, f1.w};
        union { __bf16 h[8]; uintx4 u; } ph, pl;
#pragma unroll
        for (int j = 0; j < 8; ++j) {
            __bf16 hh = (__bf16)f[j];
            ph.h[j] = hh;
            pl.h[j] = (__bf16)(f[j] - (float)hh);
        }
        *(uintx4*)(sAf + (((mt * 8 + chunk) * 64 + ln) * 8)) = ph.u;
        *(uintx4*)(sAf + (((mt * 8 + 4 + chunk) * 64 + ln) * 8)) = pl.u;
    }
    __syncthreads();

    // ---- main loop: wave owns m-tiles {2w, 2w+1} x all 16 n-tiles ----
    floatx4 acc[2][16];
#pragma unroll
    for (int m = 0; m < 2; ++m)
#pragma unroll
        for (int t = 0; t < 16; ++t) acc[m][t] = (floatx4){0.f, 0.f, 0.f, 0.f};

    const int mt0 = wave * 2;
#pragma unroll 1
    for (int kb = 0; kb < 8; ++kb) {
        const int ca = kb & 3;
        bf16x8 ah0 = *(bf16x8*)(sAf + (((mt0 * 8 + ca) * 64 + lane) * 8));
        bf16x8 al0 = *(bf16x8*)(sAf + (((mt0 * 8 + 4 + ca) * 64 + lane) * 8));
        bf16x8 ah1 = *(bf16x8*)(sAf + ((((mt0 + 1) * 8 + ca) * 64 + lane) * 8));
        bf16x8 al1 = *(bf16x8*)(sAf + ((((mt0 + 1) * 8 + 4 + ca) * 64 + lane) * 8));
        const __bf16* bbase = cbB + ((size_t)kb * 64 + lane) * 8;
#pragma unroll
        for (int t = 0; t < 16; ++t) {
            bf16x8 b = *(const bf16x8*)(bbase + (size_t)t * 4096);
            acc[0][t] = MFMA16(ah0, b, acc[0][t], 0, 0, 0);
            acc[1][t] = MFMA16(ah1, b, acc[1][t], 0, 0, 0);
            acc[0][t] = MFMA16(al0, b, acc[0][t], 0, 0, 0);
            acc[1][t] = MFMA16(al1, b, acc[1][t], 0, 0, 0);
        }
    }

    // ---- epilogue: top-2 per query row, flag near-ties ----
    float cs[16];
#pragma unroll
    for (int t = 0; t < 16; ++t) cs[t] = s_csq[t * 16 + (lane & 15)];

#pragma unroll 1
    for (int m = 0; m < 2; ++m) {
        const int mt = mt0 + m;
#pragma unroll 1
        for (int r = 0; r < 4; ++r) {
            unsigned long long b = ~0ULL, s = ~0ULL;
#pragma unroll
            for (int t = 0; t < 16; ++t) {
                const int n = t * 16 + (lane & 15);
                float score = fmaf(-2.0f, acc[m][t][r], cs[t]);
                unsigned long long key =
                    ((unsigned long long)fmap(score) << 32) | (unsigned)n;
                if (key < b) { s = b; b = key; }
                else if (key < s) { s = key; }
            }
#pragma unroll
            for (int d = 1; d < 16; d <<= 1) {
                unsigned long long ob = __shfl_xor(b, d);
                unsigned long long os = __shfl_xor(s, d);
                unsigned long long nb = ob < b ? ob : b;
                unsigned long long mx = ob < b ? b : ob;
                unsigned long long mn = os < s ? os : s;
                b = nb;
                s = mx < mn ? mx : mn;
            }
            if ((lane & 15) == 0) {
                const int row = (lane >> 4) * 4 + r;
                const size_t qg = (size_t)blockIdx.x * 128 + mt * 16 + row;
                out[qg] = (int)(unsigned)(b & 0xFFFFFFFFull);
                float f1 = unfmap((unsigned)(b >> 32));
                float f2 = unfmap((unsigned)(s >> 32));
                if (f2 - f1 < T_FLAG) {
                    int idx = atomicAdd(cnt, 1);
                    if (idx < WL_CAP) wl[idx] = (int)qg;
                }
            }
        }
    }
}

// ---------------- Phase B: exact fp32 rescan of flagged queries ----------------
__global__ __launch_bounds__(256) void knn_refine(const float* __restrict__ x,
                                                  const float* __restrict__ cb,
                                                  const int* __restrict__ wl,
                                                  const int* __restrict__ cnt,
                                                  int* __restrict__ out) {
    const int wave = threadIdx.x >> 6;
    const int lane = threadIdx.x & 63;
    const int gw = blockIdx.x * 4 + wave;
    int n = *cnt;
    if (n > WL_CAP) n = WL_CAP;
    const int stride = gridDim.x * 4;

    for (int i = gw; i < n; i += stride) {
        const int q = wl[i];
        const float4* qr = (const float4*)(x + (size_t)q * 128);
        unsigned long long best = ~0ULL;
#pragma unroll 1
        for (int j = 0; j < 4; ++j) {
            const int k = j * 64 + lane;
            const float4* cr = (const float4*)(cb + (size_t)k * 128);
            float a0 = 0.f, a1 = 0.f, a2 = 0.f, a3 = 0.f;
            float c0 = 0.f, c1 = 0.f, c2 = 0.f, c3 = 0.f;
#pragma unroll 4
            for (int c4 = 0; c4 < 32; ++c4) {
                float4 cv = cr[c4];
                float4 qv = qr[c4];
                a0 = fmaf(qv.x, cv.x, a0);
                a1 = fmaf(qv.y, cv.y, a1);
                a2 = fmaf(qv.z, cv.z, a2);
                a3 = fmaf(qv.w, cv.w, a3);
                c0 = fmaf(cv.x, cv.x, c0);
                c1 = fmaf(cv.y, cv.y, c1);
                c2 = fmaf(cv.z, cv.z, c2);
                c3 = fmaf(cv.w, cv.w, c3);
            }
            float dot = (a0 + a1) + (a2 + a3);
            float csq = (c0 + c1) + (c2 + c3);
            float score = fmaf(-2.0f, dot, csq);
            unsigned long long key =
                ((unsigned long long)fmap(score) << 32) | (unsigned)k;
            best = key < best ? key : best;
        }
#pragma unroll
        for (int d = 1; d < 64; d <<= 1) {
            unsigned long long o = __shfl_xor(best, d);
            best = o < best ? o : best;
        }
        if (lane == 0)
            out[q] = (int)(unsigned)(best & 0xFFFFFFFFull);
    }
}

extern "C" void kernel_launch(void* const* d_in, const int* in_sizes, int n_in,
                              void* d_out, int out_size, void* d_ws, size_t ws_size,
                              hipStream_t stream) {
    const float* x = (const float*)d_in[0];
    const float* cb = (const float*)d_in[1];
    int* out = (int*)d_out;

    char* ws = (char*)d_ws;
    int* cnt = (int*)(ws + CNT_OFF);
    float* csq = (float*)(ws + CSQ_OFF);
    __bf16* cbB = (__bf16*)(ws + CBB_OFF);
    int* wl = (int*)(ws + WL_OFF);

    const int M = in_sizes[0] / 128;     // 131072

    hipMemsetAsync(cnt, 0, 4, stream);
    knn_prep<<<32, 256, 0, stream>>>(cb, cbB, csq);
    knn_mfma<<<M / 128, 256, 0, stream>>>(x, cbB, csq, out, cnt, wl);
    knn_refine<<<256, 256, 0, stream>>>(x, cb, wl, cnt, out);
}

// Round 6
// 152.912 us; speedup vs baseline: 2.3999x; 1.3185x over previous
//
#include <hip/hip_runtime.h>
#include <hip/hip_bf16.h>

// 1-NN VQ via split-bf16 MFMA + exact fp32 refinement.
//   score[q][k] = csq[k] - 2*dot(q,c_k); out = argmin_k (lowest-k tie-break).
// Phase 0 (knn_prep): codebook -> bf16 hi/lo fragment-ready cbB in d_ws + csq.
// Phase A (knn_mfma): 128 queries/block; q split to (qh,ql) bf16 in LDS;
//   dot ~= qh.ch + qh.cl + ql.ch  (ql.cl dropped: |err| <= 2^-18*Sum|q||c| ~3e-4).
//   Total score error ~1.5e-3 << T/2; top-2 gap < T=0.02 -> worklist.
// Phase B (knn_refine): exact fp32 rescan of flagged queries, block-per-query.
// Round-6 changes vs r5: epilogue m/r loops FULLY unrolled (r5's unroll-1 made
//   acc[m][t][r] dynamically indexed -> whole acc array in scratch: 167 MB
//   WRITE_SIZE, 64 MB extra FETCH, MfmaUtil 12.6%). kb loop stays unroll 1
//   (r4 evidence: full kb unroll -> VGPR 256 + spill). 3-product MFMA (-25%).
//   Refine: block-per-query, csq reused from prep (exact fp32 path).

typedef __bf16 bf16x8 __attribute__((ext_vector_type(8)));
typedef float  floatx4 __attribute__((ext_vector_type(4)));
typedef unsigned uintx4 __attribute__((ext_vector_type(4)));

#define MFMA16 __builtin_amdgcn_mfma_f32_16x16x32_bf16

#define CNT_OFF 0
#define CSQ_OFF 1024
#define CBB_OFF 4096
#define WL_OFF  (4096 + 131072)
#define WL_CAP  32768
#define T_FLAG  0.02f

__device__ __forceinline__ unsigned fmap(float f) {
    unsigned u = __float_as_uint(f);
    return (u & 0x80000000u) ? ~u : (u | 0x80000000u);
}
__device__ __forceinline__ float unfmap(unsigned u) {
    unsigned b = (u & 0x80000000u) ? (u ^ 0x80000000u) : ~u;
    return __uint_as_float(b);
}

// ---------------- Phase 0: codebook split + fragment layout + csq ----------------
__global__ void knn_prep(const float* __restrict__ cb, __bf16* __restrict__ cbB,
                         float* __restrict__ csq) {
    const int tid = threadIdx.x;
    const int id = blockIdx.x * 256 + tid;       // 0..8191
    const int t = id >> 9;
    const int kb = (id >> 6) & 7;
    const int ln = id & 63;
    const int n = t * 16 + (ln & 15);
    const int part = kb >> 2;
    const int chunk = kb & 3;
    const int k0 = chunk * 32 + (ln >> 4) * 8;
    const float* src = cb + (size_t)n * 128 + k0;
    union { __bf16 h[8]; uintx4 u; } p;
#pragma unroll
    for (int j = 0; j < 8; ++j) {
        float f = src[j];
        __bf16 hh = (__bf16)f;
        p.h[j] = (part == 0) ? hh : (__bf16)(f - (float)hh);
    }
    *(uintx4*)(cbB + (size_t)id * 8) = p.u;

    if (blockIdx.x == 0) {
        const float4* row = (const float4*)(cb + (size_t)tid * 128);
        float a0 = 0.f, a1 = 0.f, a2 = 0.f, a3 = 0.f;
#pragma unroll 8
        for (int j = 0; j < 32; ++j) {
            float4 v = row[j];
            a0 = fmaf(v.x, v.x, a0);
            a1 = fmaf(v.y, v.y, a1);
            a2 = fmaf(v.z, v.z, a2);
            a3 = fmaf(v.w, v.w, a3);
        }
        csq[tid] = (a0 + a1) + (a2 + a3);
    }
}

// ---------------- Phase A: MFMA scores + top-2 + flag ----------------
__global__ __launch_bounds__(256, 2) void knn_mfma(const float* __restrict__ x,
                                                   const __bf16* __restrict__ cbB,
                                                   const float* __restrict__ csq_g,
                                                   int* __restrict__ out,
                                                   int* __restrict__ cnt,
                                                   int* __restrict__ wl) {
    __shared__ __bf16 sAf[8 * 8 * 64 * 8];   // [mt][kb][lane][8] = 64 KB
    __shared__ float s_csq[256];

    const int tid = threadIdx.x;
    const int wave = tid >> 6;
    const int lane = tid & 63;

    s_csq[tid] = csq_g[tid];

    // ---- convert query tile to split bf16, fragment-ready in LDS ----
    const float* xblk = x + (size_t)blockIdx.x * 128 * 128;
    const int chunk = wave;                  // wave w converts channel chunk w
    const int ln = tid & 63;
#pragma unroll 1
    for (int mt = 0; mt < 8; ++mt) {
        const int q = mt * 16 + (ln & 15);
        const int k0 = chunk * 32 + (ln >> 4) * 8;
        const float* src = xblk + (size_t)q * 128 + k0;
        float4 f0 = *(const float4*)(src);
        float4 f1 = *(const float4*)(src + 4);
        float f[8] = {f0.x, f0.y, f0.z, f0.w, f1.x, f1.y, f1.z, f1.w};
        union { __bf16 h[8]; uintx4 u; } ph, pl;
#pragma unroll
        for (int j = 0; j < 8; ++j) {
            __bf16 hh = (__bf16)f[j];
            ph.h[j] = hh;
            pl.h[j] = (__bf16)(f[j] - (float)hh);
        }
        *(uintx4*)(sAf + (((mt * 8 + chunk) * 64 + ln) * 8)) = ph.u;
        *(uintx4*)(sAf + (((mt * 8 + 4 + chunk) * 64 + ln) * 8)) = pl.u;
    }
    __syncthreads();

    // ---- main loop: wave owns m-tiles {2w, 2w+1} x all 16 n-tiles ----
    floatx4 acc[2][16];
#pragma unroll
    for (int m = 0; m < 2; ++m)
#pragma unroll
        for (int t = 0; t < 16; ++t) acc[m][t] = (floatx4){0.f, 0.f, 0.f, 0.f};

    const int mt0 = wave * 2;

    // Part 1: B hi chunks (kb 0..3): qh.ch + ql.ch
#pragma unroll 1
    for (int kb = 0; kb < 4; ++kb) {
        bf16x8 ah0 = *(bf16x8*)(sAf + (((mt0 * 8 + kb) * 64 + lane) * 8));
        bf16x8 al0 = *(bf16x8*)(sAf + (((mt0 * 8 + 4 + kb) * 64 + lane) * 8));
        bf16x8 ah1 = *(bf16x8*)(sAf + ((((mt0 + 1) * 8 + kb) * 64 + lane) * 8));
        bf16x8 al1 = *(bf16x8*)(sAf + ((((mt0 + 1) * 8 + 4 + kb) * 64 + lane) * 8));
        const __bf16* bbase = cbB + ((size_t)kb * 64 + lane) * 8;
#pragma unroll
        for (int t = 0; t < 16; ++t) {
            bf16x8 b = *(const bf16x8*)(bbase + (size_t)t * 4096);
            acc[0][t] = MFMA16(ah0, b, acc[0][t], 0, 0, 0);
            acc[1][t] = MFMA16(ah1, b, acc[1][t], 0, 0, 0);
            acc[0][t] = MFMA16(al0, b, acc[0][t], 0, 0, 0);
            acc[1][t] = MFMA16(al1, b, acc[1][t], 0, 0, 0);
        }
    }
    // Part 2: B lo chunks (kb 4..7): qh.cl only (ql.cl dropped)
#pragma unroll 1
    for (int kb = 4; kb < 8; ++kb) {
        const int ca = kb & 3;
        bf16x8 ah0 = *(bf16x8*)(sAf + (((mt0 * 8 + ca) * 64 + lane) * 8));
        bf16x8 ah1 = *(bf16x8*)(sAf + ((((mt0 + 1) * 8 + ca) * 64 + lane) * 8));
        const __bf16* bbase = cbB + ((size_t)kb * 64 + lane) * 8;
#pragma unroll
        for (int t = 0; t < 16; ++t) {
            bf16x8 b = *(const bf16x8*)(bbase + (size_t)t * 4096);
            acc[0][t] = MFMA16(ah0, b, acc[0][t], 0, 0, 0);
            acc[1][t] = MFMA16(ah1, b, acc[1][t], 0, 0, 0);
        }
    }

    // ---- epilogue: top-2 per query row, flag near-ties ----
    // FULLY unrolled m/r: acc[m][t][r] must be constant-indexed (r5 lesson:
    // unroll-1 here -> dynamic index -> whole acc in scratch, 167 MB writes).
    float cs[16];
#pragma unroll
    for (int t = 0; t < 16; ++t) cs[t] = s_csq[t * 16 + (lane & 15)];

#pragma unroll
    for (int m = 0; m < 2; ++m) {
        const int mt = mt0 + m;
#pragma unroll
        for (int r = 0; r < 4; ++r) {
            unsigned long long b = ~0ULL, s = ~0ULL;
#pragma unroll
            for (int t = 0; t < 16; ++t) {
                const int n = t * 16 + (lane & 15);
                float score = fmaf(-2.0f, acc[m][t][r], cs[t]);
                unsigned long long key =
                    ((unsigned long long)fmap(score) << 32) | (unsigned)n;
                if (key < b) { s = b; b = key; }
                else if (key < s) { s = key; }
            }
#pragma unroll
            for (int d = 1; d < 16; d <<= 1) {
                unsigned long long ob = __shfl_xor(b, d);
                unsigned long long os = __shfl_xor(s, d);
                unsigned long long nb = ob < b ? ob : b;
                unsigned long long mx = ob < b ? b : ob;
                unsigned long long mn = os < s ? os : s;
                b = nb;
                s = mx < mn ? mx : mn;
            }
            if ((lane & 15) == 0) {
                const int row = (lane >> 4) * 4 + r;
                const size_t qg = (size_t)blockIdx.x * 128 + mt * 16 + row;
                out[qg] = (int)(unsigned)(b & 0xFFFFFFFFull);
                float f1 = unfmap((unsigned)(b >> 32));
                float f2 = unfmap((unsigned)(s >> 32));
                if (f2 - f1 < T_FLAG) {
                    int idx = atomicAdd(cnt, 1);
                    if (idx < WL_CAP) wl[idx] = (int)qg;
                }
            }
        }
    }
}

// ---------------- Phase B: exact fp32 rescan, block-per-query ----------------
__global__ __launch_bounds__(256) void knn_refine(const float* __restrict__ x,
                                                  const float* __restrict__ cb,
                                                  const float* __restrict__ csq_g,
                                                  const int* __restrict__ wl,
                                                  const int* __restrict__ cnt,
                                                  int* __restrict__ out) {
    __shared__ unsigned long long sP[4];
    const int tid = threadIdx.x;           // == code index k
    const int lane = tid & 63;
    const int wave = tid >> 6;

    int n = *cnt;
    if (n > WL_CAP) n = WL_CAP;
    const float mycsq = csq_g[tid];
    const float4* cr = (const float4*)(cb + (size_t)tid * 128);

    for (int i = blockIdx.x; i < n; i += gridDim.x) {
        const int q = wl[i];
        const float4* qr = (const float4*)(x + (size_t)q * 128);
        float a0 = 0.f, a1 = 0.f, a2 = 0.f, a3 = 0.f;
#pragma unroll 8
        for (int c4 = 0; c4 < 32; ++c4) {
            float4 qv = qr[c4];            // broadcast (same addr all lanes)
            float4 cv = cr[c4];
            a0 = fmaf(qv.x, cv.x, a0);
            a1 = fmaf(qv.y, cv.y, a1);
            a2 = fmaf(qv.z, cv.z, a2);
            a3 = fmaf(qv.w, cv.w, a3);
        }
        float dot = (a0 + a1) + (a2 + a3);
        float score = fmaf(-2.0f, dot, mycsq);
        unsigned long long key =
            ((unsigned long long)fmap(score) << 32) | (unsigned)tid;
#pragma unroll
        for (int d = 1; d < 64; d <<= 1) {
            unsigned long long o = __shfl_xor(key, d);
            key = o < key ? o : key;
        }
        if (lane == 0) sP[wave] = key;
        __syncthreads();
        if (tid == 0) {
            unsigned long long b = sP[0];
            unsigned long long o;
            o = sP[1]; b = o < b ? o : b;
            o = sP[2]; b = o < b ? o : b;
            o = sP[3]; b = o < b ? o : b;
            out[q] = (int)(unsigned)(b & 0xFFFFFFFFull);
        }
        __syncthreads();
    }
}

extern "C" void kernel_launch(void* const* d_in, const int* in_sizes, int n_in,
                              void* d_out, int out_size, void* d_ws, size_t ws_size,
                              hipStream_t stream) {
    const float* x = (const float*)d_in[0];
    const float* cb = (const float*)d_in[1];
    int* out = (int*)d_out;

    char* ws = (char*)d_ws;
    int* cnt = (int*)(ws + CNT_OFF);
    float* csq = (float*)(ws + CSQ_OFF);
    __bf16* cbB = (__bf16*)(ws + CBB_OFF);
    int* wl = (int*)(ws + WL_OFF);

    const int M = in_sizes[0] / 128;     // 131072

    hipMemsetAsync(cnt, 0, 4, stream);
    knn_prep<<<32, 256, 0, stream>>>(cb, cbB, csq);
    knn_mfma<<<M / 128, 256, 0, stream>>>(x, cbB, csq, out, cnt, wl);
    knn_refine<<<120, 256, 0, stream>>>(x, cb, csq, wl, cnt, out);
}